// Round 1
// baseline (76.723 us; speedup 1.0000x reference)
//
#include <hip/hip_runtime.h>
#include <math.h>

// Quantum circuit: 4 qubits, 2 layers, one thread per batch sample.
// State = 16 complex amps in registers (re[16], im[16]), qubit0 = MSB
// (reference: wire q -> axis q+1 of [B,2,2,2,2], so flat stride = 8>>q).

#define HALF_PI_F 1.57079632679489661923f

__global__ __launch_bounds__(256) void qlayer_kernel(
    const float* __restrict__ x,
    const float* __restrict__ weight,
    float* __restrict__ out,
    int B)
{
    // Batch-uniform weight trig -> LDS (16 weights: [layer(2), qubit(4), {ry,rz}(2)])
    __shared__ float cw[16], sw[16];
    if (threadIdx.x < 16) {
        float h = 0.5f * weight[threadIdx.x];
        __sincosf(h, &sw[threadIdx.x], &cw[threadIdx.x]);
    }
    __syncthreads();

    int tid = blockIdx.x * blockDim.x + threadIdx.x;
    if (tid >= B) return;

    float4 xv = reinterpret_cast<const float4*>(x)[tid];

    // Angle encoding: half-angle = tanh(x)*pi/2; RY on |0> -> [cos, sin]
    float c[4], s[4];
    {
        float xs[4] = {xv.x, xv.y, xv.z, xv.w};
        #pragma unroll
        for (int q = 0; q < 4; ++q) {
            float t = tanhf(xs[q]);
            __sincosf(t * HALF_PI_F, &s[q], &c[q]);
        }
    }

    // Initial state: real product state
    float re[16], im[16];
    {
        float p01[4] = {c[0]*c[1], c[0]*s[1], s[0]*c[1], s[0]*s[1]};
        float p23[4] = {c[2]*c[3], c[2]*s[3], s[2]*c[3], s[2]*s[3]};
        #pragma unroll
        for (int a = 0; a < 4; ++a)
            #pragma unroll
            for (int b = 0; b < 4; ++b) {
                re[a*4+b] = p01[a]*p23[b];
                im[a*4+b] = 0.0f;
            }
    }

    #pragma unroll
    for (int layer = 0; layer < 2; ++layer) {
        // Fused RY(weight[l,q,0]) then RZ(weight[l,q,1]) per qubit
        #pragma unroll
        for (int q = 0; q < 4; ++q) {
            float cy = cw[layer*8 + q*2 + 0];
            float sy = sw[layer*8 + q*2 + 0];
            float cz = cw[layer*8 + q*2 + 1];
            float sz = sw[layer*8 + q*2 + 1];
            int st = 8 >> q;
            #pragma unroll
            for (int i = 0; i < 16; ++i) {
                if (i & st) continue;
                int j = i | st;
                float r0 = re[i], r1 = re[j], i0 = im[i], i1 = im[j];
                // RY: [c,-s;s,c]
                float nr0 = cy*r0 - sy*r1;
                float nr1 = sy*r0 + cy*r1;
                float ni0 = cy*i0 - sy*i1;
                float ni1 = sy*i0 + cy*i1;
                // RZ: diag(e^{-i hz}, e^{+i hz}); e^{-i hz} = (cz, -sz)
                re[i] = nr0*cz + ni0*sz;
                im[i] = ni0*cz - nr0*sz;
                re[j] = nr1*cz - ni1*sz;
                im[j] = ni1*cz + nr1*sz;
            }
        }
        // CNOT ring: control q -> target (q+1)%4. Pure register permutation.
        #pragma unroll
        for (int q = 0; q < 4; ++q) {
            int cb = 8 >> q;
            int tb = 8 >> ((q + 1) & 3);
            #pragma unroll
            for (int i = 0; i < 16; ++i) {
                if ((i & cb) && !(i & tb)) {
                    int j = i | tb;
                    float tr = re[i]; re[i] = re[j]; re[j] = tr;
                    float ti = im[i]; im[i] = im[j]; im[j] = ti;
                }
            }
        }
    }

    // <Z_q> = sum_i sign_q(i) * |amp_i|^2
    float p[16];
    #pragma unroll
    for (int i = 0; i < 16; ++i) p[i] = re[i]*re[i] + im[i]*im[i];

    float z[4] = {0.f, 0.f, 0.f, 0.f};
    #pragma unroll
    for (int i = 0; i < 16; ++i) {
        #pragma unroll
        for (int q = 0; q < 4; ++q)
            z[q] += (i & (8 >> q)) ? -p[i] : p[i];
    }

    float4 o = {z[0], z[1], z[2], z[3]};
    reinterpret_cast<float4*>(out)[tid] = o;
}

extern "C" void kernel_launch(void* const* d_in, const int* in_sizes, int n_in,
                              void* d_out, int out_size, void* d_ws, size_t ws_size,
                              hipStream_t stream) {
    const float* x = (const float*)d_in[0];
    const float* w = (const float*)d_in[1];
    float* out = (float*)d_out;
    int B = in_sizes[0] / 4;
    int block = 256;
    int grid = (B + block - 1) / block;
    qlayer_kernel<<<grid, block, 0, stream>>>(x, w, out, B);
}

// Round 2
// 73.788 us; speedup vs baseline: 1.0398x; 1.0398x over previous
//
#include <hip/hip_runtime.h>
#include <math.h>

// QuantumLayer: 4 qubits, 2 layers, batch 524288.
//
// Key identity: final state psi = U * p, where U is a batch-UNIFORM 16x16
// complex unitary (only weight-dependent) and p is the real product state
// from the angle encoding: p = a (x) b, a/b = 4-dim factors of qubits 0,1 / 2,3.
// Then  z_q = p^T A^q p,  A^q_jk = sum_i sign_q(i) Re(U_ij conj(U_ik))  (real sym).
// Fold Kronecker + symmetry:  z_q = sum_{Pi,Qi} C^q[Pi][Qi] P[Pi] Q[Qi]
// with P/Q the 10 unordered pair products of a/b. C = 4x10x10 floats, built
// once per call by a 1-block setup kernel into d_ws, then consumed via
// uniform (scalar) loads in the main kernel.

#define HALF_PI_F 1.57079632679489661923f

__global__ __launch_bounds__(256) void build_C(
    const float* __restrict__ weight,
    float* __restrict__ C)  // [4][10][10]
{
    __shared__ float cw[16], sw[16];
    __shared__ float Ur[16][16], Ui[16][16];  // U[i][j]
    __shared__ float A[4][16][16];

    if (threadIdx.x < 16) {
        float h = 0.5f * weight[threadIdx.x];
        __sincosf(h, &sw[threadIdx.x], &cw[threadIdx.x]);
    }
    __syncthreads();

    // Threads 0..15: column j of U = circuit applied to basis vector e_j.
    if (threadIdx.x < 16) {
        int col = threadIdx.x;
        float re[16], im[16];
        #pragma unroll
        for (int i = 0; i < 16; ++i) { re[i] = 0.f; im[i] = 0.f; }
        re[col] = 1.f;

        #pragma unroll
        for (int layer = 0; layer < 2; ++layer) {
            #pragma unroll
            for (int q = 0; q < 4; ++q) {
                float cy = cw[layer*8 + q*2 + 0];
                float sy = sw[layer*8 + q*2 + 0];
                float cz = cw[layer*8 + q*2 + 1];
                float sz = sw[layer*8 + q*2 + 1];
                int st = 8 >> q;
                #pragma unroll
                for (int i = 0; i < 16; ++i) {
                    if (i & st) continue;
                    int j = i | st;
                    float r0 = re[i], r1 = re[j], i0 = im[i], i1 = im[j];
                    float nr0 = cy*r0 - sy*r1;
                    float nr1 = sy*r0 + cy*r1;
                    float ni0 = cy*i0 - sy*i1;
                    float ni1 = sy*i0 + cy*i1;
                    re[i] = nr0*cz + ni0*sz;
                    im[i] = ni0*cz - nr0*sz;
                    re[j] = nr1*cz - ni1*sz;
                    im[j] = ni1*cz + nr1*sz;
                }
            }
            #pragma unroll
            for (int q = 0; q < 4; ++q) {
                int cb = 8 >> q;
                int tb = 8 >> ((q + 1) & 3);
                #pragma unroll
                for (int i = 0; i < 16; ++i) {
                    if ((i & cb) && !(i & tb)) {
                        int j = i | tb;
                        float tr = re[i]; re[i] = re[j]; re[j] = tr;
                        float ti = im[i]; im[i] = im[j]; im[j] = ti;
                    }
                }
            }
        }
        #pragma unroll
        for (int i = 0; i < 16; ++i) { Ur[i][col] = re[i]; Ui[i][col] = im[i]; }
    }
    __syncthreads();

    // A[q][j][k] = sum_i sign_q(i) (Ur[i][j]Ur[i][k] + Ui[i][j]Ui[i][k])
    for (int e = threadIdx.x; e < 1024; e += 256) {
        int q = e >> 8, j = (e >> 4) & 15, k = e & 15;
        float sum = 0.f;
        for (int i = 0; i < 16; ++i) {
            float t = Ur[i][j]*Ur[i][k] + Ui[i][j]*Ui[i][k];
            sum += (i & (8 >> q)) ? -t : t;
        }
        A[q][j][k] = sum;
    }
    __syncthreads();

    // C[q][Pi][Qi] = sum over ordered realizations of unordered pairs.
    for (int e = threadIdx.x; e < 400; e += 256) {
        int q = e / 100, pi = (e / 10) % 10, qi = e % 10;
        const int pu[10] = {0,0,0,0,1,1,1,2,2,3};
        const int pv[10] = {0,1,2,3,1,2,3,2,3,3};
        int u = pu[pi], v = pv[pi], r = pu[qi], s = pv[qi];
        float sum = 0.f;
        int a1s[2] = {u, v}, a2s[2] = {v, u};
        int b1s[2] = {r, s}, b2s[2] = {s, r};
        int na = (u == v) ? 1 : 2;
        int nb = (r == s) ? 1 : 2;
        for (int ia = 0; ia < na; ++ia)
            for (int ib = 0; ib < nb; ++ib)
                sum += A[q][a1s[ia]*4 + b1s[ib]][a2s[ia]*4 + b2s[ib]];
        C[e] = sum;
    }
}

__global__ __launch_bounds__(256) void qmain(
    const float* __restrict__ x,
    const float* __restrict__ C,   // [4][10][10], batch-uniform -> scalar loads
    float* __restrict__ out,
    int B)
{
    int tid = blockIdx.x * blockDim.x + threadIdx.x;
    if (tid >= B) return;

    float4 xv = reinterpret_cast<const float4*>(x)[tid];
    float xs[4] = {xv.x, xv.y, xv.z, xv.w};

    float c[4], s[4];
    #pragma unroll
    for (int q = 0; q < 4; ++q) {
        // tanh(x) = 1 - 2/(e^{2x}+1); fast exp + fast divide (err ~1e-6,
        // threshold is 2e-2)
        float e = __expf(2.f * xs[q]);
        float t = 1.f - __fdividef(2.f, e + 1.f);
        __sincosf(t * HALF_PI_F, &s[q], &c[q]);
    }

    float a4[4] = {c[0]*c[1], c[0]*s[1], s[0]*c[1], s[0]*s[1]};
    float b4[4] = {c[2]*c[3], c[2]*s[3], s[2]*c[3], s[2]*s[3]};

    const int pu[10] = {0,0,0,0,1,1,1,2,2,3};
    const int pv[10] = {0,1,2,3,1,2,3,2,3,3};
    float P[10], Q[10];
    #pragma unroll
    for (int i2 = 0; i2 < 10; ++i2) {
        P[i2] = a4[pu[i2]] * a4[pv[i2]];
        Q[i2] = b4[pu[i2]] * b4[pv[i2]];
    }

    float z[4];
    #pragma unroll
    for (int q = 0; q < 4; ++q) {
        float zq = 0.f;
        #pragma unroll
        for (int pi = 0; pi < 10; ++pi) {
            float t = 0.f;
            #pragma unroll
            for (int qi = 0; qi < 10; ++qi)
                t = fmaf(C[q*100 + pi*10 + qi], Q[qi], t);
            zq = fmaf(P[pi], t, zq);
        }
        z[q] = zq;
    }

    float4 o = {z[0], z[1], z[2], z[3]};
    reinterpret_cast<float4*>(out)[tid] = o;
}

extern "C" void kernel_launch(void* const* d_in, const int* in_sizes, int n_in,
                              void* d_out, int out_size, void* d_ws, size_t ws_size,
                              hipStream_t stream) {
    const float* x = (const float*)d_in[0];
    const float* w = (const float*)d_in[1];
    float* out = (float*)d_out;
    float* C = (float*)d_ws;  // 400 floats
    int B = in_sizes[0] / 4;

    build_C<<<1, 256, 0, stream>>>(w, C);
    int block = 256;
    int grid = (B + block - 1) / block;
    qmain<<<grid, block, 0, stream>>>(x, C, out, B);
}